// Round 14
// baseline (5354480.078 us; speedup 1.0000x reference)
//
#include <hip/hip_runtime.h>

#define BB 256
#define TT 512
#define HH 512
#define NTH 256
#define SLOTG 65536          // granules per slot (256 b x 256 jp), 1 MB
#define ESC_N 200            // sticky escalation threshold (L2 fast path -> L3 mirror)
#define SPIN_CAP (1 << 13)   // absolute cap: fail-visible, never hang

typedef float    f32x4 __attribute__((ext_vector_type(4)));
typedef float    f32x2 __attribute__((ext_vector_type(2)));
typedef unsigned u32x4 __attribute__((ext_vector_type(4)));
typedef unsigned u32x2 __attribute__((ext_vector_type(2)));
typedef short    bf16x8 __attribute__((ext_vector_type(8)));

__device__ __forceinline__ f32x4 mfma16(u32x4 a, u32x4 b, f32x4 c) {
    return __builtin_amdgcn_mfma_f32_16x16x32_bf16(
        __builtin_bit_cast(bf16x8, a), __builtin_bit_cast(bf16x8, b), c, 0, 0, 0);
}
__device__ __forceinline__ unsigned rne16(float f) {
    unsigned u = __builtin_bit_cast(unsigned, f);
    return (u + 0x7FFFu + ((u >> 16) & 1u)) >> 16;
}

// frag range [F0,F1): 2 ds_read_b128 + 6 MFMA per frag (6 indep chains, 2 m-tiles)
#define PH(F0, F1)                                                             \
    { _Pragma("unroll")                                                        \
      for (int f = (F0); f < (F1); ++f) {                                      \
          const int kb = (4 * q + f) & 15;                                     \
          u32x4 bh = *reinterpret_cast<const u32x4*>(&SH[kb * 256 + l * 4]);   \
          u32x4 bl = *reinterpret_cast<const u32x4*>(&SL[kb * 256 + l * 4]);   \
          Ch0 = mfma16(Ahi[0][f], bh, Ch0);                                    \
          Ch1 = mfma16(Ahi[1][f], bh, Ch1);                                    \
          Cd0 = mfma16(Ahi[0][f], bl, Cd0);                                    \
          Cd1 = mfma16(Ahi[1][f], bl, Cd1);                                    \
          Ce0 = mfma16(Alo[0][f], bh, Ce0);                                    \
          Ce1 = mfma16(Alo[1][f], bh, Ce1);                                    \
      } }

#define ISSUE12P(BASE)                                                         \
    { _Pragma("unroll")                                                        \
      for (int jx = 0; jx < 12; ++jx)                                          \
          asm volatile("global_load_dwordx4 %0, %1, off sc0"                   \
                       : "=&v"(G[jx]) : "v"((BASE) + goff[jx]) : "memory"); }
#define ISSUE12M(BASE)                                                         \
    { _Pragma("unroll")                                                        \
      for (int jx = 0; jx < 12; ++jx)                                          \
          asm volatile("global_load_dwordx4 %0, %1, off sc0 sc1"               \
                       : "=&v"(G[jx]) : "v"((BASE) + goff[jx]) : "memory"); }

// XCD-local quad-split MFMA RNN (bf16-split fp32 emulation, R10 machinery).
// 64 WGs: xcd = bid&7 (round-robin dispatch), member q = (bid>>3)&3,
// quad = xcd*2 + (bid>>5). Quad owns 16 batches; WG q owns j-rows [128q,+128).
// Exchange: 16B granules (hi-pair, lo-pair, tag, tag), ping-pong by t&1.
// FAST path: sc0 stores/loads through the quad's shared per-XCD L2.
// SAFETY net: every granule mirrored with sc0sc1 (L3); readers stickily
// escalate to the mirror after ESC_N failed polls -> correct under ANY
// workgroup->XCD mapping. Spin-capped: failure is visible, never a hang.
__global__ void __attribute__((amdgpu_flat_work_group_size(NTH, NTH)))
__attribute__((amdgpu_waves_per_eu(1, 1)))
rnn_xq(const float* __restrict__ x,    // [B, T, 2]
       const float* __restrict__ Wh,   // [H, H]
       const float* __restrict__ Wx,   // [H, 2]
       float* __restrict__ out,        // [T+1, B, H]
       u32x4* __restrict__ ws)         // P[2][256][256] + M[2][256][256] (4 MB)
{
    const int bid = blockIdx.x, tid = threadIdx.x;
    const int q   = (bid >> 3) & 3;              // quad member (same XCD under %8)
    const int QD  = (bid & 7) * 2 + (bid >> 5);  // quad id 0..15
    const int b0  = QD * 16;
    const int w   = tid >> 6, l = tid & 63;
    const int col = l & 15, qr = l >> 4;
    const int J0  = 128 * q;

    __shared__ unsigned SH[4096];        // hi-plane B staging, frag-linear (16 KB)
    __shared__ unsigned SL[4096];        // lo-plane (16 KB)
    __shared__ float    xsb[16 * 1028];  // x stash, padded stride (64.2 KB) -> 1 WG/CU

    // ---- x stash: 16 batches x 1024 floats, coalesced ----
    #pragma unroll
    for (int it = 0; it < 16; ++it) {
        int idx = it * 256 + tid;
        f32x4 v = reinterpret_cast<const f32x4*>(x + (size_t)b0 * (TT * 2))[idx];
        *reinterpret_cast<f32x4*>(&xsb[(idx >> 8) * 1028 + (idx & 255) * 4]) = v;
    }

    // ---- A-frags (R10 verbatim): wave w owns m-tiles 2w, 2w+1 (16 rows each);
    //      rotation-indexed frag f <-> global k-block (4q+f)&15 ----
    u32x4 Ahi[2][16], Alo[2][16];
    #pragma unroll
    for (int i = 0; i < 2; ++i) {
        const float* rp = Wh + (size_t)(J0 + (2 * w + i) * 16 + col) * HH + qr * 8;
        #pragma unroll
        for (int f = 0; f < 16; ++f) {
            const int kb = (4 * q + f) & 15;
            const f32x4* p = reinterpret_cast<const f32x4*>(rp + kb * 32);
            f32x4 v0 = p[0], v1 = p[1];
            float fv[8] = {v0[0], v0[1], v0[2], v0[3], v1[0], v1[1], v1[2], v1[3]};
            u32x4 hi, lo;
            #pragma unroll
            for (int r = 0; r < 4; ++r) {
                unsigned h0 = rne16(fv[2*r]);
                unsigned l0 = rne16(fv[2*r]   - __builtin_bit_cast(float, h0 << 16));
                unsigned h1 = rne16(fv[2*r+1]);
                unsigned l1 = rne16(fv[2*r+1] - __builtin_bit_cast(float, h1 << 16));
                hi[r] = h0 | (h1 << 16);
                lo[r] = l0 | (l1 << 16);
            }
            Ahi[i][f] = hi; Alo[i][f] = lo;
        }
    }

    // ---- Wx coefficients ----
    float wxa[2][4], wxb[2][4];
    #pragma unroll
    for (int i = 0; i < 2; ++i)
        #pragma unroll
        for (int r = 0; r < 4; ++r) {
            int j = J0 + (2 * w + i) * 16 + qr * 4 + r;
            wxa[i][r] = Wx[2 * j]; wxb[i][r] = Wx[2 * j + 1];
        }

    // ---- zero staging; h0 (e0, all 16 batches) staged FULLY locally; out[0] ----
    {
        u32x4 zz = {0u, 0u, 0u, 0u};
        #pragma unroll
        for (int it = 0; it < 4; ++it) {
            reinterpret_cast<u32x4*>(SH)[it * 256 + tid] = zz;
            reinterpret_cast<u32x4*>(SL)[it * 256 + tid] = zz;
        }
    }
    #pragma unroll
    for (int it = 0; it < 2; ++it) {
        int idx = it * 256 + tid;                 // 512 = 16 b x 32 j-quads
        int b = idx >> 5, jq = idx & 31;
        f32x4 z; z[0] = (J0 + jq * 4 == 0) ? 1.f : 0.f; z[1] = 0.f; z[2] = 0.f; z[3] = 0.f;
        *reinterpret_cast<f32x4*>(out + (size_t)(b0 + b) * HH + J0 + jq * 4) = z;
    }
    __syncthreads();
    if (tid < 16) SH[tid * 4] = 0x3F80u;          // h0[k=0]=1.0 bf16, batch=tid

    // ---- loader map: 12 remote granules/thread (3 quarters x 4 adjacent jp) ----
    int goff[12], lddb[3];
    {
        const int lb = tid & 15, sub = tid >> 4;   // batch, jp-subgroup 0..15
        #pragma unroll
        for (int jx = 0; jx < 12; ++jx) {
            const int Qq = (q + 1 + (jx >> 2)) & 3;
            goff[jx] = (b0 + lb) * 256 + Qq * 64 + sub * 4 + (jx & 3);
        }
        #pragma unroll
        for (int gi = 0; gi < 3; ++gi) {
            const int Qq = (q + 1 + gi) & 3;
            lddb[gi] = (Qq * 4 + (sub >> 2)) * 256 + (sub & 3) * 64 + lb * 4;
        }
    }
    __syncthreads();

    const f32x4 Z = {0.f, 0.f, 0.f, 0.f};
    u32x4 G[12];
    int esc = 0;

    for (int t = 0; t < TT; ++t) {
        const unsigned Tg = (unsigned)t, T1u = Tg + 1u;
        const int s = t & 1, s1 = s ^ 1;
        u32x4* Pc = ws + (size_t)s * SLOTG;
        u32x4* Mc = ws + 2 * SLOTG + (size_t)s * SLOTG;
        u32x4* Pn = ws + (size_t)s1 * SLOTG;
        u32x4* Mn = ws + 2 * SLOTG + (size_t)s1 * SLOTG;

        // A. issue remote loads (fast L2 path, or mirror if escalated)
        if (t > 0) { if (esc) ISSUE12M(Mc) else ISSUE12P(Pc) }

        // B. phase1: own quarter (frags 0..3) -- covers part of the latency
        f32x4 Ch0 = Z, Ch1 = Z, Cd0 = Z, Cd1 = Z, Ce0 = Z, Ce1 = Z;
        PH(0, 4)

        // C. spin on tags; land 3x b128 per plane
        if (t > 0) {
            int guard = 0;
            for (;;) {
                asm volatile("s_waitcnt vmcnt(0)" ::: "memory");
                __builtin_amdgcn_sched_barrier(0);
                int ok = 1;
                #pragma unroll
                for (int jx = 0; jx < 12; ++jx)
                    ok &= (int)(G[jx].z == Tg) & (int)(G[jx].w == Tg);
                if (__all(ok)) break;
                if (++guard > SPIN_CAP) break;
                if (guard >= ESC_N) esc = 1;
                if (esc) ISSUE12M(Mc) else ISSUE12P(Pc)
            }
            #pragma unroll
            for (int gi = 0; gi < 3; ++gi) {
                u32x4 hv, lv;
                hv[0] = G[gi*4+0].x; hv[1] = G[gi*4+1].x;
                hv[2] = G[gi*4+2].x; hv[3] = G[gi*4+3].x;
                lv[0] = G[gi*4+0].y; lv[1] = G[gi*4+1].y;
                lv[2] = G[gi*4+2].y; lv[3] = G[gi*4+3].y;
                *reinterpret_cast<u32x4*>(&SH[lddb[gi]]) = hv;
                *reinterpret_cast<u32x4*>(&SL[lddb[gi]]) = lv;
            }
        }
        __syncthreads();   // B1: full h(t) staged

        // D. phase2: remote three quarters (frags 4..15)
        PH(4, 16)

        // E. epilogue: x-projection + ReLU; publish fast+mirror; stage own; out
        {
            f32x2 xv = *reinterpret_cast<const f32x2*>(&xsb[col * 1028 + 2 * t]);
            #pragma unroll
            for (int i = 0; i < 2; ++i) {
                f32x4 C = (i ? Ch1 : Ch0) + (i ? Cd1 : Cd0) + (i ? Ce1 : Ce0);
                const int j0 = J0 + (2 * w + i) * 16 + qr * 4;
                f32x4 v; unsigned h_[4], l_[4];
                #pragma unroll
                for (int r = 0; r < 4; ++r) {
                    v[r] = fmaxf(C[r] + wxa[i][r] * xv[0] + wxb[i][r] * xv[1], 0.f);
                    h_[r] = rne16(v[r]);
                    l_[r] = rne16(v[r] - __builtin_bit_cast(float, h_[r] << 16));
                }
                const unsigned H0 = h_[0] | (h_[1] << 16), L0 = l_[0] | (l_[1] << 16);
                const unsigned H1 = h_[2] | (h_[3] << 16), L1 = l_[2] | (l_[3] << 16);
                u32x4 ga = {H0, L0, T1u, T1u}, gb = {H1, L1, T1u, T1u};
                const size_t gidx = (size_t)(b0 + col) * 256 + (j0 >> 1);
                asm volatile("global_store_dwordx4 %0, %2, off sc0\n\t"
                             "global_store_dwordx4 %1, %3, off sc0"
                             :: "v"(Pn + gidx), "v"(Pn + gidx + 1), "v"(ga), "v"(gb)
                             : "memory");
                asm volatile("global_store_dwordx4 %0, %2, off sc0 sc1\n\t"
                             "global_store_dwordx4 %1, %3, off sc0 sc1"
                             :: "v"(Mn + gidx), "v"(Mn + gidx + 1), "v"(ga), "v"(gb)
                             : "memory");
                const int d0 = (j0 >> 5) * 256 + ((j0 >> 3) & 3) * 64
                             + col * 4 + ((j0 & 7) >> 1);
                *reinterpret_cast<u32x2*>(&SH[d0]) = u32x2{H0, H1};
                *reinterpret_cast<u32x2*>(&SL[d0]) = u32x2{L0, L1};
                *reinterpret_cast<f32x4*>(out + (size_t)(t + 1) * (BB * HH)
                                              + (size_t)(b0 + col) * HH + j0) = v;
            }
        }
        __syncthreads();   // B2: own region of staging updated for next phase1
    }
}

extern "C" void kernel_launch(void* const* d_in, const int* in_sizes, int n_in,
                              void* d_out, int out_size, void* d_ws, size_t ws_size,
                              hipStream_t stream) {
    const float* x  = (const float*)d_in[0];
    const float* Wh = (const float*)d_in[1];
    const float* Wx = (const float*)d_in[2];
    float* out = (float*)d_out;
    u32x4* ws = (u32x4*)d_ws;    // 4 slots x 65536 granules x 16 B = 4 MB
    rnn_xq<<<64, NTH, 0, stream>>>(x, Wh, Wx, out, ws);
}